// Round 1
// baseline (768.544 us; speedup 1.0000x reference)
//
#include <hip/hip_runtime.h>
#include <math.h>

#define NB 8          // batch
#define NC 4          // sim channels
#define HW 802816     // 896*896
#define LMAX 16
#define TPB 256
#define IPT 16
#define PXB (TPB*IPT)     // 4096 pixels per block
#define BPB (HW/PXB)      // 196 blocks per batch (exact)

struct WS {
    float seg_ker[NB][LMAX];        // sum kernels_gt over lab_k segments
    float seg_sim[NB][NC][LMAX];    // sum sims over lab_k segments
    float seg_reg[NB][LMAX];        // sum kernels_gt over lab_r segments (bug-faithful)
    float seg_n  [NB][LMAX];        // pixel counts over lab_k segments
    int   kmax   [NB];              // max(lab_k) per batch
    float dice[6];                  // sum(pr*rg), sum(pr), sum(rg), sum(pk*kg), sum(pk), sum(kg)
    float lagg;                     // sum log(nrm^2+1)/(card_r+1)  (divide by num_k_last at end)
};

__device__ __forceinline__ float waveReduceSum(float v) {
#pragma unroll
    for (int off = 32; off > 0; off >>= 1) v += __shfl_down(v, off, 64);
    return v;
}

__global__ __launch_bounds__(TPB) void pan_pass1(
    const float* __restrict__ predR, const float* __restrict__ regGT,
    const float* __restrict__ predK, const float* __restrict__ kerGT,
    const float* __restrict__ sims,  const int* __restrict__ labR,
    const int* __restrict__ labK, WS* __restrict__ ws)
{
    const int b   = blockIdx.x / BPB;
    const int blk = blockIdx.x % BPB;
    const size_t pb = (size_t)b * HW;
    const int q0 = blk * PXB;

    __shared__ float s_ker[LMAX], s_reg[LMAX], s_n[LMAX], s_sim[NC][LMAX];
    if (threadIdx.x < LMAX) {
        s_ker[threadIdx.x] = 0.f; s_reg[threadIdx.x] = 0.f; s_n[threadIdx.x] = 0.f;
#pragma unroll
        for (int c = 0; c < NC; ++c) s_sim[c][threadIdx.x] = 0.f;
    }
    __syncthreads();

    float d0=0.f,d1=0.f,d2=0.f,d3=0.f,d4=0.f,d5=0.f;
    int km = 0;
#pragma unroll 4
    for (int i = 0; i < IPT; ++i) {
        const int q = q0 + i*TPB + threadIdx.x;
        const size_t p = pb + q;
        const float rg = regGT[p];
        const float kg = kerGT[p];
        const float sr = 1.f / (1.f + __expf(-predR[p]));   // sigmoid
        const float sk = 1.f / (1.f + __expf(-predK[p]));
        const float prm = sr * rg;    // sigmoid(pred_regions) * ohem (ohem = regions_gt)
        const float rgm = rg * rg;    // regions_gt * ohem
        d0 += prm * rgm; d1 += prm; d2 += rgm;
        d3 += sk * kg;   d4 += sk;  d5 += kg;

        const int lk = labK[p] & (LMAX-1);
        const int lr = labR[p] & (LMAX-1);
        km = max(km, lk);
        atomicAdd(&s_ker[lk], kg);
        atomicAdd(&s_reg[lr], kg);
        atomicAdd(&s_n[lk], 1.f);
#pragma unroll
        for (int c = 0; c < NC; ++c)
            atomicAdd(&s_sim[c][lk], sims[((size_t)(b*NC + c))*HW + q]);
    }

    d0 = waveReduceSum(d0); d1 = waveReduceSum(d1); d2 = waveReduceSum(d2);
    d3 = waveReduceSum(d3); d4 = waveReduceSum(d4); d5 = waveReduceSum(d5);
#pragma unroll
    for (int off = 32; off > 0; off >>= 1) km = max(km, __shfl_down(km, off, 64));
    if ((threadIdx.x & 63) == 0) {
        atomicAdd(&ws->dice[0], d0); atomicAdd(&ws->dice[1], d1);
        atomicAdd(&ws->dice[2], d2); atomicAdd(&ws->dice[3], d3);
        atomicAdd(&ws->dice[4], d4); atomicAdd(&ws->dice[5], d5);
        atomicMax(&ws->kmax[b], km);
    }
    __syncthreads();
    if (threadIdx.x < LMAX) {
        atomicAdd(&ws->seg_ker[b][threadIdx.x], s_ker[threadIdx.x]);
        atomicAdd(&ws->seg_reg[b][threadIdx.x], s_reg[threadIdx.x]);
        atomicAdd(&ws->seg_n[b][threadIdx.x],   s_n[threadIdx.x]);
#pragma unroll
        for (int c = 0; c < NC; ++c)
            atomicAdd(&ws->seg_sim[b][c][threadIdx.x], s_sim[c][threadIdx.x]);
    }
}

__global__ __launch_bounds__(TPB) void pan_pass2(
    const float* __restrict__ regGT, const float* __restrict__ sims,
    const int* __restrict__ labR, const int* __restrict__ labK,
    WS* __restrict__ ws)
{
    const int b   = blockIdx.x / BPB;
    const int blk = blockIdx.x % BPB;
    const size_t pb = (size_t)b * HW;
    const int q0 = blk * PXB;

    __shared__ float s_ker[LMAX], s_reg[LMAX], s_sim[NC][LMAX];
    if (threadIdx.x < LMAX) {
        s_ker[threadIdx.x] = ws->seg_ker[b][threadIdx.x];
        s_reg[threadIdx.x] = ws->seg_reg[b][threadIdx.x];
#pragma unroll
        for (int c = 0; c < NC; ++c) s_sim[c][threadIdx.x] = ws->seg_sim[b][c][threadIdx.x];
    }
    __syncthreads();

    float acc = 0.f;
#pragma unroll 4
    for (int i = 0; i < IPT; ++i) {
        const int q = q0 + i*TPB + threadIdx.x;
        const size_t p = pb + q;
        const int lk = labK[p] & (LMAX-1);
        const int lr = labR[p] & (LMAX-1);
        const float rg = regGT[p];
        const float ck = (lk > 0) ? s_ker[lk] : 0.f;   // card_k
        const float cr = (lr > 0) ? s_reg[lr] : 0.f;   // card_r
        const float inv = 1.f / (ck + 1.f);
        float sq = 0.f;
#pragma unroll
        for (int c = 0; c < NC; ++c) {
            const float Fp = sims[((size_t)(b*NC + c))*HW + q] * rg;
            const float G  = (lk > 0) ? s_sim[c][lk] * inv : 0.f;
            const float d  = Fp - G;
            sq += d * d;
        }
        float nr = (sq > 0.f) ? sqrtf(sq) : 0.f;
        nr -= 0.5f;                      // SIGMA_AGG
        nr  = fmaxf(nr, 0.f);
        acc += __logf(nr*nr + 1.f) / (cr + 1.f);
    }
    acc = waveReduceSum(acc);
    if ((threadIdx.x & 63) == 0) atomicAdd(&ws->lagg, acc);
}

__global__ void pan_finalize(const WS* __restrict__ ws, float* __restrict__ out)
{
    if (threadIdx.x != 0 || blockIdx.x != 0) return;
    const double f0 = log(10.0);   // log(SIGMA_DIS^2 + 1)
    double Ldis = 0.0;
    for (int b = 0; b < NB; ++b) {
        const int K = ws->kmax[b];
        if (K >= 2) {
            double t1 = 0.0;
            const int lim = (K < LMAX-1) ? K : (LMAX-1);
            for (int l = 1; l <= lim; ++l) {
                float sqS = 0.f;
                for (int c = 0; c < NC; ++c) {
                    const float s = ws->seg_sim[b][c][l];
                    sqS += s * s;
                }
                const float nm  = (sqS > 0.f) ? sqrtf(sqS) : 0.f;
                float gap = 3.0f - nm;            // SIGMA_DIS
                gap = fmaxf(gap, 0.f);
                const double f = log((double)gap*gap + 1.0);
                t1 += (double)ws->seg_n[b][l] * (f - f0);
            }
            Ldis += (K - 1.0) * t1
                  + (double)K * (K - 1) * 0.5 * (double)NB * (double)HW * f0;
        }
    }
    const double numk = (double)ws->kmax[NB-1];
    const double Lagg = (double)ws->lagg / numk;
    const double lr = 1.0 - (2.0*(double)ws->dice[0] + 1e-6) /
                            ((double)ws->dice[1] + (double)ws->dice[2] + 1e-6);
    const double lk = 1.0 - (2.0*(double)ws->dice[3] + 1e-6) /
                            ((double)ws->dice[4] + (double)ws->dice[5] + 1e-6);
    out[0] = (float)(lr + 0.5*lk + 0.25*(Lagg + Ldis));
}

extern "C" void kernel_launch(void* const* d_in, const int* in_sizes, int n_in,
                              void* d_out, int out_size, void* d_ws, size_t ws_size,
                              hipStream_t stream)
{
    const float* predR = (const float*)d_in[0];
    const float* regGT = (const float*)d_in[1];
    const float* predK = (const float*)d_in[2];
    const float* kerGT = (const float*)d_in[3];
    const float* sims  = (const float*)d_in[4];
    const int*   labR  = (const int*)d_in[5];   // text_mask_ndi_labels
    const int*   labK  = (const int*)d_in[6];   // kernel_mask_ndi_labels
    WS* ws = (WS*)d_ws;

    hipMemsetAsync(d_ws, 0, sizeof(WS), stream);

    dim3 grid(NB * BPB), blk(TPB);
    pan_pass1<<<grid, blk, 0, stream>>>(predR, regGT, predK, kerGT, sims, labR, labK, ws);
    pan_pass2<<<grid, blk, 0, stream>>>(regGT, sims, labR, labK, ws);
    pan_finalize<<<1, 64, 0, stream>>>(ws, (float*)d_out);
}

// Round 2
// 349.746 us; speedup vs baseline: 2.1974x; 2.1974x over previous
//
#include <hip/hip_runtime.h>
#include <math.h>

#define NB 8          // batch
#define NC 4          // sim channels
#define HW 802816     // 896*896
#define LMAX 16
#define TPB 256
#define NWAVE (TPB/64)
#define IPT 16
#define PXB (TPB*IPT)     // 4096 pixels per block
#define BPB (HW/PXB)      // 196 blocks per batch (exact)

#define NREP 16           // replicated LDS segment tables
#define NV 7              // values per label: ker, reg, n, sim0..3
#define RS (NV*LMAX + 1)  // 113-float stride -> copies start on different banks

struct WS {
    float seg_ker[NB][LMAX];        // sum kernels_gt over lab_k segments
    float seg_sim[NB][NC][LMAX];    // sum sims over lab_k segments
    float seg_reg[NB][LMAX];        // sum kernels_gt over lab_r segments (bug-faithful)
    float seg_n  [NB][LMAX];        // pixel counts over lab_k segments
    int   kmax   [NB];              // max(lab_k) per batch
    float dice[6];                  // sum(pr*rg), sum(pr), sum(rg), sum(pk*kg), sum(pk), sum(kg)
    float lagg;                     // sum log(nrm^2+1)/(card_r+1)
};

__device__ __forceinline__ float waveReduceSum(float v) {
#pragma unroll
    for (int off = 32; off > 0; off >>= 1) v += __shfl_down(v, off, 64);
    return v;
}

__global__ __launch_bounds__(TPB) void pan_pass1(
    const float* __restrict__ predR, const float* __restrict__ regGT,
    const float* __restrict__ predK, const float* __restrict__ kerGT,
    const float* __restrict__ sims,  const int* __restrict__ labR,
    const int* __restrict__ labK, WS* __restrict__ ws)
{
    const int b   = blockIdx.x / BPB;
    const int blk = blockIdx.x % BPB;
    const size_t pb = (size_t)b * HW;
    const int q0 = blk * PXB;

    __shared__ float s_tab[NREP][RS];
    __shared__ float s_dice[NWAVE][6];
    __shared__ int   s_km[NWAVE];
    for (int i = threadIdx.x; i < NREP*RS; i += TPB) ((float*)s_tab)[i] = 0.f;
    __syncthreads();

    float* tab = s_tab[threadIdx.x & (NREP-1)];

    float d0=0.f,d1=0.f,d2=0.f,d3=0.f,d4=0.f,d5=0.f;
    int km = 0;
    for (int i = 0; i < IPT; ++i) {
        const int q = q0 + i*TPB + threadIdx.x;
        const size_t p = pb + q;
        const float rg = regGT[p];
        const float kg = kerGT[p];
        const float sr = 1.f / (1.f + __expf(-predR[p]));   // sigmoid
        const float sk = 1.f / (1.f + __expf(-predK[p]));
        const float prm = sr * rg;    // sigmoid(pred_regions) * ohem (ohem = regions_gt)
        const float rgm = rg * rg;    // regions_gt * ohem
        d0 += prm * rgm; d1 += prm; d2 += rgm;
        d3 += sk * kg;   d4 += sk;  d5 += kg;

        const int lk = labK[p] & (LMAX-1);
        const int lr = labR[p] & (LMAX-1);
        km = max(km, lk);
        unsafeAtomicAdd(&tab[0*LMAX + lk], kg);
        unsafeAtomicAdd(&tab[1*LMAX + lr], kg);
        unsafeAtomicAdd(&tab[2*LMAX + lk], 1.f);
#pragma unroll
        for (int c = 0; c < NC; ++c)
            unsafeAtomicAdd(&tab[(3+c)*LMAX + lk],
                            sims[((size_t)(b*NC + c))*HW + q]);
    }

    d0 = waveReduceSum(d0); d1 = waveReduceSum(d1); d2 = waveReduceSum(d2);
    d3 = waveReduceSum(d3); d4 = waveReduceSum(d4); d5 = waveReduceSum(d5);
#pragma unroll
    for (int off = 32; off > 0; off >>= 1) km = max(km, __shfl_down(km, off, 64));
    const int wid = threadIdx.x >> 6;
    if ((threadIdx.x & 63) == 0) {
        s_dice[wid][0]=d0; s_dice[wid][1]=d1; s_dice[wid][2]=d2;
        s_dice[wid][3]=d3; s_dice[wid][4]=d4; s_dice[wid][5]=d5;
        s_km[wid]=km;
    }
    __syncthreads();

    // one global atomic per block per scalar (hardware fadd)
    if (threadIdx.x < 6) {
        float s = 0.f;
#pragma unroll
        for (int w = 0; w < NWAVE; ++w) s += s_dice[w][threadIdx.x];
        unsafeAtomicAdd(&ws->dice[threadIdx.x], s);
    } else if (threadIdx.x == 6) {
        int m = s_km[0];
#pragma unroll
        for (int w = 1; w < NWAVE; ++w) m = max(m, s_km[w]);
        atomicMax(&ws->kmax[b], m);
    }

    // flush replicated segment tables: 112 slots, each summed over 16 reps
    if (threadIdx.x < NV*LMAX) {
        const int v = threadIdx.x >> 4;   // value index
        const int l = threadIdx.x & 15;   // label
        float s = 0.f;
#pragma unroll
        for (int r = 0; r < NREP; ++r) s += s_tab[r][v*LMAX + l];
        float* dst;
        if      (v == 0) dst = &ws->seg_ker[b][l];
        else if (v == 1) dst = &ws->seg_reg[b][l];
        else if (v == 2) dst = &ws->seg_n[b][l];
        else             dst = &ws->seg_sim[b][v-3][l];
        unsafeAtomicAdd(dst, s);
    }
}

__global__ __launch_bounds__(TPB) void pan_pass2(
    const float* __restrict__ regGT, const float* __restrict__ sims,
    const int* __restrict__ labR, const int* __restrict__ labK,
    WS* __restrict__ ws)
{
    const int b   = blockIdx.x / BPB;
    const int blk = blockIdx.x % BPB;
    const size_t pb = (size_t)b * HW;
    const int q0 = blk * PXB;

    __shared__ float s_ker[LMAX], s_reg[LMAX], s_sim[NC][LMAX];
    __shared__ float s_l[NWAVE];
    if (threadIdx.x < LMAX) {
        s_ker[threadIdx.x] = ws->seg_ker[b][threadIdx.x];
        s_reg[threadIdx.x] = ws->seg_reg[b][threadIdx.x];
#pragma unroll
        for (int c = 0; c < NC; ++c) s_sim[c][threadIdx.x] = ws->seg_sim[b][c][threadIdx.x];
    }
    __syncthreads();

    float acc = 0.f;
    for (int i = 0; i < IPT; ++i) {
        const int q = q0 + i*TPB + threadIdx.x;
        const size_t p = pb + q;
        const int lk = labK[p] & (LMAX-1);
        const int lr = labR[p] & (LMAX-1);
        const float rg = regGT[p];
        const float ck = (lk > 0) ? s_ker[lk] : 0.f;   // card_k
        const float cr = (lr > 0) ? s_reg[lr] : 0.f;   // card_r
        const float inv = 1.f / (ck + 1.f);
        float sq = 0.f;
#pragma unroll
        for (int c = 0; c < NC; ++c) {
            const float Fp = sims[((size_t)(b*NC + c))*HW + q] * rg;
            const float G  = (lk > 0) ? s_sim[c][lk] * inv : 0.f;
            const float d  = Fp - G;
            sq += d * d;
        }
        float nr = (sq > 0.f) ? sqrtf(sq) : 0.f;
        nr -= 0.5f;                      // SIGMA_AGG
        nr  = fmaxf(nr, 0.f);
        acc += __logf(nr*nr + 1.f) / (cr + 1.f);
    }
    acc = waveReduceSum(acc);
    const int wid = threadIdx.x >> 6;
    if ((threadIdx.x & 63) == 0) s_l[wid] = acc;
    __syncthreads();
    if (threadIdx.x == 0) {
        float s = 0.f;
#pragma unroll
        for (int w = 0; w < NWAVE; ++w) s += s_l[w];
        unsafeAtomicAdd(&ws->lagg, s);
    }
}

__global__ void pan_finalize(const WS* __restrict__ ws, float* __restrict__ out)
{
    if (threadIdx.x != 0 || blockIdx.x != 0) return;
    const double f0 = log(10.0);   // log(SIGMA_DIS^2 + 1)
    double Ldis = 0.0;
    for (int b = 0; b < NB; ++b) {
        const int K = ws->kmax[b];
        if (K >= 2) {
            double t1 = 0.0;
            const int lim = (K < LMAX-1) ? K : (LMAX-1);
            for (int l = 1; l <= lim; ++l) {
                float sqS = 0.f;
                for (int c = 0; c < NC; ++c) {
                    const float s = ws->seg_sim[b][c][l];
                    sqS += s * s;
                }
                const float nm  = (sqS > 0.f) ? sqrtf(sqS) : 0.f;
                float gap = 3.0f - nm;            // SIGMA_DIS
                gap = fmaxf(gap, 0.f);
                const double f = log((double)gap*gap + 1.0);
                t1 += (double)ws->seg_n[b][l] * (f - f0);
            }
            Ldis += (K - 1.0) * t1
                  + (double)K * (K - 1) * 0.5 * (double)NB * (double)HW * f0;
        }
    }
    const double numk = (double)ws->kmax[NB-1];
    const double Lagg = (double)ws->lagg / numk;
    const double lr = 1.0 - (2.0*(double)ws->dice[0] + 1e-6) /
                            ((double)ws->dice[1] + (double)ws->dice[2] + 1e-6);
    const double lk = 1.0 - (2.0*(double)ws->dice[3] + 1e-6) /
                            ((double)ws->dice[4] + (double)ws->dice[5] + 1e-6);
    out[0] = (float)(lr + 0.5*lk + 0.25*(Lagg + Ldis));
}

extern "C" void kernel_launch(void* const* d_in, const int* in_sizes, int n_in,
                              void* d_out, int out_size, void* d_ws, size_t ws_size,
                              hipStream_t stream)
{
    const float* predR = (const float*)d_in[0];
    const float* regGT = (const float*)d_in[1];
    const float* predK = (const float*)d_in[2];
    const float* kerGT = (const float*)d_in[3];
    const float* sims  = (const float*)d_in[4];
    const int*   labR  = (const int*)d_in[5];   // text_mask_ndi_labels
    const int*   labK  = (const int*)d_in[6];   // kernel_mask_ndi_labels
    WS* ws = (WS*)d_ws;

    hipMemsetAsync(d_ws, 0, sizeof(WS), stream);

    dim3 grid(NB * BPB), blk(TPB);
    pan_pass1<<<grid, blk, 0, stream>>>(predR, regGT, predK, kerGT, sims, labR, labK, ws);
    pan_pass2<<<grid, blk, 0, stream>>>(regGT, sims, labR, labK, ws);
    pan_finalize<<<1, 64, 0, stream>>>(ws, (float*)d_out);
}

// Round 3
// 342.859 us; speedup vs baseline: 2.2416x; 1.0201x over previous
//
#include <hip/hip_runtime.h>
#include <math.h>

#define NB 8          // batch
#define NC 4          // sim channels
#define HW 802816     // 896*896
#define LMAX 16
#define TPB 256
#define NWAVE (TPB/64)
#define VEC 4
#define IPTV 4                  // vector iterations per thread
#define PXB (TPB*VEC*IPTV)      // 4096 pixels per block
#define BPB (HW/PXB)            // 196 blocks per batch (exact)

#define NREP 16           // replicated LDS segment tables
#define NV 7              // values per label: ker, reg, n, sim0..3
#define RS (NV*LMAX + 1)  // 113-float stride -> copies start on different banks

struct WS {
    float seg_ker[NB][LMAX];
    float seg_sim[NB][NC][LMAX];
    float seg_reg[NB][LMAX];
    float seg_n  [NB][LMAX];
    int   kmax   [NB];
    float dice[6];
    float lagg;
};

__device__ __forceinline__ float waveReduceSum(float v) {
#pragma unroll
    for (int off = 32; off > 0; off >>= 1) v += __shfl_down(v, off, 64);
    return v;
}

__global__ __launch_bounds__(TPB) void pan_pass1(
    const float* __restrict__ predR, const float* __restrict__ regGT,
    const float* __restrict__ predK, const float* __restrict__ kerGT,
    const float* __restrict__ sims,  const int* __restrict__ labR,
    const int* __restrict__ labK, WS* __restrict__ ws)
{
    const int b   = blockIdx.x / BPB;
    const int blk = blockIdx.x % BPB;
    const size_t pb = (size_t)b * HW;
    const int q0 = blk * PXB;

    __shared__ float s_tab[NREP][RS];
    __shared__ float s_dice[NWAVE][6];
    __shared__ int   s_km[NWAVE];
    for (int i = threadIdx.x; i < NREP*RS; i += TPB) ((float*)s_tab)[i] = 0.f;
    __syncthreads();

    float* tab = s_tab[threadIdx.x & (NREP-1)];

    float d0=0.f,d1=0.f,d2=0.f,d3=0.f,d4=0.f,d5=0.f;
    int km = 0;
#pragma unroll
    for (int i = 0; i < IPTV; ++i) {
        const int q = q0 + ((i*TPB + threadIdx.x) << 2);
        const size_t p = pb + q;
        const float4 rg4 = *(const float4*)(regGT + p);
        const float4 kg4 = *(const float4*)(kerGT + p);
        const float4 pr4 = *(const float4*)(predR + p);
        const float4 pk4 = *(const float4*)(predK + p);
        const float4 s0  = *(const float4*)(sims + ((size_t)(b*NC+0))*HW + q);
        const float4 s1  = *(const float4*)(sims + ((size_t)(b*NC+1))*HW + q);
        const float4 s2  = *(const float4*)(sims + ((size_t)(b*NC+2))*HW + q);
        const float4 s3  = *(const float4*)(sims + ((size_t)(b*NC+3))*HW + q);
        const int4 lk4 = *(const int4*)(labK + p);
        const int4 lr4 = *(const int4*)(labR + p);

        const float rgA[VEC] = {rg4.x, rg4.y, rg4.z, rg4.w};
        const float kgA[VEC] = {kg4.x, kg4.y, kg4.z, kg4.w};
        const float prA[VEC] = {pr4.x, pr4.y, pr4.z, pr4.w};
        const float pkA[VEC] = {pk4.x, pk4.y, pk4.z, pk4.w};
        const float smA[NC][VEC] = {{s0.x,s0.y,s0.z,s0.w},{s1.x,s1.y,s1.z,s1.w},
                                    {s2.x,s2.y,s2.z,s2.w},{s3.x,s3.y,s3.z,s3.w}};
        const int lkA[VEC] = {lk4.x, lk4.y, lk4.z, lk4.w};
        const int lrA[VEC] = {lr4.x, lr4.y, lr4.z, lr4.w};

#pragma unroll
        for (int j = 0; j < VEC; ++j) {
            const float rg = rgA[j], kg = kgA[j];
            const float sr = 1.f / (1.f + __expf(-prA[j]));
            const float sk = 1.f / (1.f + __expf(-pkA[j]));
            const float prm = sr * rg;
            const float rgm = rg * rg;
            d0 += prm * rgm; d1 += prm; d2 += rgm;
            d3 += sk * kg;   d4 += sk;  d5 += kg;

            const int lk = lkA[j] & (LMAX-1);
            const int lr = lrA[j] & (LMAX-1);
            km = max(km, lk);
            unsafeAtomicAdd(&tab[0*LMAX + lk], kg);
            unsafeAtomicAdd(&tab[1*LMAX + lr], kg);
            unsafeAtomicAdd(&tab[2*LMAX + lk], 1.f);
#pragma unroll
            for (int c = 0; c < NC; ++c)
                unsafeAtomicAdd(&tab[(3+c)*LMAX + lk], smA[c][j]);
        }
    }

    d0 = waveReduceSum(d0); d1 = waveReduceSum(d1); d2 = waveReduceSum(d2);
    d3 = waveReduceSum(d3); d4 = waveReduceSum(d4); d5 = waveReduceSum(d5);
#pragma unroll
    for (int off = 32; off > 0; off >>= 1) km = max(km, __shfl_down(km, off, 64));
    const int wid = threadIdx.x >> 6;
    if ((threadIdx.x & 63) == 0) {
        s_dice[wid][0]=d0; s_dice[wid][1]=d1; s_dice[wid][2]=d2;
        s_dice[wid][3]=d3; s_dice[wid][4]=d4; s_dice[wid][5]=d5;
        s_km[wid]=km;
    }
    __syncthreads();

    if (threadIdx.x < 6) {
        float s = 0.f;
#pragma unroll
        for (int w = 0; w < NWAVE; ++w) s += s_dice[w][threadIdx.x];
        unsafeAtomicAdd(&ws->dice[threadIdx.x], s);
    } else if (threadIdx.x == 6) {
        int m = s_km[0];
#pragma unroll
        for (int w = 1; w < NWAVE; ++w) m = max(m, s_km[w]);
        atomicMax(&ws->kmax[b], m);
    }

    if (threadIdx.x < NV*LMAX) {
        const int v = threadIdx.x >> 4;
        const int l = threadIdx.x & 15;
        float s = 0.f;
#pragma unroll
        for (int r = 0; r < NREP; ++r) s += s_tab[r][v*LMAX + l];
        float* dst;
        if      (v == 0) dst = &ws->seg_ker[b][l];
        else if (v == 1) dst = &ws->seg_reg[b][l];
        else if (v == 2) dst = &ws->seg_n[b][l];
        else             dst = &ws->seg_sim[b][v-3][l];
        unsafeAtomicAdd(dst, s);
    }
}

__global__ __launch_bounds__(TPB) void pan_pass2(
    const float* __restrict__ regGT, const float* __restrict__ sims,
    const int* __restrict__ labR, const int* __restrict__ labK,
    WS* __restrict__ ws)
{
    const int b   = blockIdx.x / BPB;
    const int blk = blockIdx.x % BPB;
    const size_t pb = (size_t)b * HW;
    const int q0 = blk * PXB;

    __shared__ float s_ker[LMAX], s_reg[LMAX], s_sim[NC][LMAX];
    __shared__ float s_l[NWAVE];
    if (threadIdx.x < LMAX) {
        s_ker[threadIdx.x] = ws->seg_ker[b][threadIdx.x];
        s_reg[threadIdx.x] = ws->seg_reg[b][threadIdx.x];
#pragma unroll
        for (int c = 0; c < NC; ++c) s_sim[c][threadIdx.x] = ws->seg_sim[b][c][threadIdx.x];
    }
    __syncthreads();

    float acc = 0.f;
#pragma unroll
    for (int i = 0; i < IPTV; ++i) {
        const int q = q0 + ((i*TPB + threadIdx.x) << 2);
        const size_t p = pb + q;
        const float4 rg4 = *(const float4*)(regGT + p);
        const float4 s0  = *(const float4*)(sims + ((size_t)(b*NC+0))*HW + q);
        const float4 s1  = *(const float4*)(sims + ((size_t)(b*NC+1))*HW + q);
        const float4 s2  = *(const float4*)(sims + ((size_t)(b*NC+2))*HW + q);
        const float4 s3  = *(const float4*)(sims + ((size_t)(b*NC+3))*HW + q);
        const int4 lk4 = *(const int4*)(labK + p);
        const int4 lr4 = *(const int4*)(labR + p);

        const float rgA[VEC] = {rg4.x, rg4.y, rg4.z, rg4.w};
        const float smA[NC][VEC] = {{s0.x,s0.y,s0.z,s0.w},{s1.x,s1.y,s1.z,s1.w},
                                    {s2.x,s2.y,s2.z,s2.w},{s3.x,s3.y,s3.z,s3.w}};
        const int lkA[VEC] = {lk4.x, lk4.y, lk4.z, lk4.w};
        const int lrA[VEC] = {lr4.x, lr4.y, lr4.z, lr4.w};

#pragma unroll
        for (int j = 0; j < VEC; ++j) {
            const int lk = lkA[j] & (LMAX-1);
            const int lr = lrA[j] & (LMAX-1);
            const float rg = rgA[j];
            const float ck = (lk > 0) ? s_ker[lk] : 0.f;
            const float cr = (lr > 0) ? s_reg[lr] : 0.f;
            const float inv = 1.f / (ck + 1.f);
            float sq = 0.f;
#pragma unroll
            for (int c = 0; c < NC; ++c) {
                const float Fp = smA[c][j] * rg;
                const float G  = (lk > 0) ? s_sim[c][lk] * inv : 0.f;
                const float d  = Fp - G;
                sq += d * d;
            }
            float nr = (sq > 0.f) ? sqrtf(sq) : 0.f;
            nr -= 0.5f;
            nr  = fmaxf(nr, 0.f);
            acc += __logf(nr*nr + 1.f) / (cr + 1.f);
        }
    }
    acc = waveReduceSum(acc);
    const int wid = threadIdx.x >> 6;
    if ((threadIdx.x & 63) == 0) s_l[wid] = acc;
    __syncthreads();
    if (threadIdx.x == 0) {
        float s = 0.f;
#pragma unroll
        for (int w = 0; w < NWAVE; ++w) s += s_l[w];
        unsafeAtomicAdd(&ws->lagg, s);
    }
}

__global__ void pan_finalize(const WS* __restrict__ ws, float* __restrict__ out)
{
    if (threadIdx.x != 0 || blockIdx.x != 0) return;
    const double f0 = log(10.0);
    double Ldis = 0.0;
    for (int b = 0; b < NB; ++b) {
        const int K = ws->kmax[b];
        if (K >= 2) {
            double t1 = 0.0;
            const int lim = (K < LMAX-1) ? K : (LMAX-1);
            for (int l = 1; l <= lim; ++l) {
                float sqS = 0.f;
                for (int c = 0; c < NC; ++c) {
                    const float s = ws->seg_sim[b][c][l];
                    sqS += s * s;
                }
                const float nm  = (sqS > 0.f) ? sqrtf(sqS) : 0.f;
                float gap = 3.0f - nm;
                gap = fmaxf(gap, 0.f);
                const double f = log((double)gap*gap + 1.0);
                t1 += (double)ws->seg_n[b][l] * (f - f0);
            }
            Ldis += (K - 1.0) * t1
                  + (double)K * (K - 1) * 0.5 * (double)NB * (double)HW * f0;
        }
    }
    const double numk = (double)ws->kmax[NB-1];
    const double Lagg = (double)ws->lagg / numk;
    const double lr = 1.0 - (2.0*(double)ws->dice[0] + 1e-6) /
                            ((double)ws->dice[1] + (double)ws->dice[2] + 1e-6);
    const double lk = 1.0 - (2.0*(double)ws->dice[3] + 1e-6) /
                            ((double)ws->dice[4] + (double)ws->dice[5] + 1e-6);
    out[0] = (float)(lr + 0.5*lk + 0.25*(Lagg + Ldis));
}

extern "C" void kernel_launch(void* const* d_in, const int* in_sizes, int n_in,
                              void* d_out, int out_size, void* d_ws, size_t ws_size,
                              hipStream_t stream)
{
    const float* predR = (const float*)d_in[0];
    const float* regGT = (const float*)d_in[1];
    const float* predK = (const float*)d_in[2];
    const float* kerGT = (const float*)d_in[3];
    const float* sims  = (const float*)d_in[4];
    const int*   labR  = (const int*)d_in[5];
    const int*   labK  = (const int*)d_in[6];
    WS* ws = (WS*)d_ws;

    hipMemsetAsync(d_ws, 0, sizeof(WS), stream);

    dim3 grid(NB * BPB), blk(TPB);
    pan_pass1<<<grid, blk, 0, stream>>>(predR, regGT, predK, kerGT, sims, labR, labK, ws);
    pan_pass2<<<grid, blk, 0, stream>>>(regGT, sims, labR, labK, ws);
    pan_finalize<<<1, 64, 0, stream>>>(ws, (float*)d_out);
}

// Round 4
// 340.625 us; speedup vs baseline: 2.2563x; 1.0066x over previous
//
#include <hip/hip_runtime.h>
#include <math.h>

#define NB 8          // batch
#define NC 4          // sim channels
#define HW 802816     // 896*896
#define LMAX 16
#define TPB 256
#define NWAVE (TPB/64)
#define VEC 4
#define IPTV 4                  // vector iterations per thread
#define PXB (TPB*VEC*IPTV)      // 4096 pixels per block
#define BPB (HW/PXB)            // 196 blocks per batch (exact)

#define NV 7              // values per label: ker, reg, n, sim0..3
#define NENT (NV*LMAX)    // 112 entries
// LDS accumulators: tab[entry][lane]  -> float idx = e*64 + lane
// bank = lane mod 32 (label-invariant): 2 lanes/bank, no same-address in-wave.

struct WS {
    float seg_ker[NB][LMAX];
    float seg_sim[NB][NC][LMAX];
    float seg_reg[NB][LMAX];
    float seg_n  [NB][LMAX];
    int   kmax   [NB];
    float dice[6];
    float lagg;
};

__device__ __forceinline__ float waveReduceSum(float v) {
#pragma unroll
    for (int off = 32; off > 0; off >>= 1) v += __shfl_down(v, off, 64);
    return v;
}

__global__ __launch_bounds__(TPB) void pan_pass1(
    const float* __restrict__ predR, const float* __restrict__ regGT,
    const float* __restrict__ predK, const float* __restrict__ kerGT,
    const float* __restrict__ sims,  const int* __restrict__ labR,
    const int* __restrict__ labK, WS* __restrict__ ws)
{
    const int b   = blockIdx.x / BPB;
    const int blk = blockIdx.x % BPB;
    const size_t pb = (size_t)b * HW;
    const int q0 = blk * PXB;
    const int lane = threadIdx.x & 63;

    __shared__ float s_tab[NENT * 64];
    __shared__ float s_dice[NWAVE][6];
    __shared__ int   s_km[NWAVE];
    for (int i = threadIdx.x; i < (NENT*64)/4; i += TPB)
        ((float4*)s_tab)[i] = make_float4(0.f, 0.f, 0.f, 0.f);
    __syncthreads();

    float d0=0.f,d1=0.f,d2=0.f,d3=0.f,d4=0.f,d5=0.f;
    int km = 0;
#pragma unroll
    for (int i = 0; i < IPTV; ++i) {
        const int q = q0 + ((i*TPB + threadIdx.x) << 2);
        const size_t p = pb + q;
        const float4 rg4 = *(const float4*)(regGT + p);
        const float4 kg4 = *(const float4*)(kerGT + p);
        const float4 pr4 = *(const float4*)(predR + p);
        const float4 pk4 = *(const float4*)(predK + p);
        const float4 s0  = *(const float4*)(sims + ((size_t)(b*NC+0))*HW + q);
        const float4 s1  = *(const float4*)(sims + ((size_t)(b*NC+1))*HW + q);
        const float4 s2  = *(const float4*)(sims + ((size_t)(b*NC+2))*HW + q);
        const float4 s3  = *(const float4*)(sims + ((size_t)(b*NC+3))*HW + q);
        const int4 lk4 = *(const int4*)(labK + p);
        const int4 lr4 = *(const int4*)(labR + p);

        const float rgA[VEC] = {rg4.x, rg4.y, rg4.z, rg4.w};
        const float kgA[VEC] = {kg4.x, kg4.y, kg4.z, kg4.w};
        const float prA[VEC] = {pr4.x, pr4.y, pr4.z, pr4.w};
        const float pkA[VEC] = {pk4.x, pk4.y, pk4.z, pk4.w};
        const float smA[NC][VEC] = {{s0.x,s0.y,s0.z,s0.w},{s1.x,s1.y,s1.z,s1.w},
                                    {s2.x,s2.y,s2.z,s2.w},{s3.x,s3.y,s3.z,s3.w}};
        const int lkA[VEC] = {lk4.x, lk4.y, lk4.z, lk4.w};
        const int lrA[VEC] = {lr4.x, lr4.y, lr4.z, lr4.w};

#pragma unroll
        for (int j = 0; j < VEC; ++j) {
            const float rg = rgA[j], kg = kgA[j];
            const float sr = 1.f / (1.f + __expf(-prA[j]));
            const float sk = 1.f / (1.f + __expf(-pkA[j]));
            const float prm = sr * rg;
            const float rgm = rg * rg;
            d0 += prm * rgm; d1 += prm; d2 += rgm;
            d3 += sk * kg;   d4 += sk;  d5 += kg;

            const int lk = lkA[j] & (LMAX-1);
            const int lr = lrA[j] & (LMAX-1);
            km = max(km, lk);
            // entry = v*16 + label; address = entry*64 + lane (bank = lane%32)
            unsafeAtomicAdd(&s_tab[((0*LMAX + lk) << 6) + lane], kg);
            unsafeAtomicAdd(&s_tab[((1*LMAX + lr) << 6) + lane], kg);
            unsafeAtomicAdd(&s_tab[((2*LMAX + lk) << 6) + lane], 1.f);
#pragma unroll
            for (int c = 0; c < NC; ++c)
                unsafeAtomicAdd(&s_tab[(((3+c)*LMAX + lk) << 6) + lane], smA[c][j]);
        }
    }

    d0 = waveReduceSum(d0); d1 = waveReduceSum(d1); d2 = waveReduceSum(d2);
    d3 = waveReduceSum(d3); d4 = waveReduceSum(d4); d5 = waveReduceSum(d5);
#pragma unroll
    for (int off = 32; off > 0; off >>= 1) km = max(km, __shfl_down(km, off, 64));
    const int wid = threadIdx.x >> 6;
    if ((threadIdx.x & 63) == 0) {
        s_dice[wid][0]=d0; s_dice[wid][1]=d1; s_dice[wid][2]=d2;
        s_dice[wid][3]=d3; s_dice[wid][4]=d4; s_dice[wid][5]=d5;
        s_km[wid]=km;
    }
    __syncthreads();

    if (threadIdx.x < 6) {
        float s = 0.f;
#pragma unroll
        for (int w = 0; w < NWAVE; ++w) s += s_dice[w][threadIdx.x];
        unsafeAtomicAdd(&ws->dice[threadIdx.x], s);
    } else if (threadIdx.x == 6) {
        int m = s_km[0];
#pragma unroll
        for (int w = 1; w < NWAVE; ++w) m = max(m, s_km[w]);
        atomicMax(&ws->kmax[b], m);
    }

    // flush: thread t (<112) sums entry t over 64 lane-columns.
    // rotated float4 walk: offset 4*((k+t)&15) -> 2-way banks, no hotspot.
    if (threadIdx.x < NENT) {
        const int e = threadIdx.x;
        const float* col = &s_tab[e << 6];
        float4 a = make_float4(0.f, 0.f, 0.f, 0.f);
#pragma unroll
        for (int k = 0; k < 16; ++k) {
            const float4 v4 = *(const float4*)(col + 4*((k + e) & 15));
            a.x += v4.x; a.y += v4.y; a.z += v4.z; a.w += v4.w;
        }
        const float s = (a.x + a.y) + (a.z + a.w);
        const int v = e >> 4;
        const int l = e & 15;
        float* dst;
        if      (v == 0) dst = &ws->seg_ker[b][l];
        else if (v == 1) dst = &ws->seg_reg[b][l];
        else if (v == 2) dst = &ws->seg_n[b][l];
        else             dst = &ws->seg_sim[b][v-3][l];
        unsafeAtomicAdd(dst, s);
    }
}

__global__ __launch_bounds__(TPB) void pan_pass2(
    const float* __restrict__ regGT, const float* __restrict__ sims,
    const int* __restrict__ labR, const int* __restrict__ labK,
    WS* __restrict__ ws)
{
    const int b   = blockIdx.x / BPB;
    const int blk = blockIdx.x % BPB;
    const size_t pb = (size_t)b * HW;
    const int q0 = blk * PXB;

    __shared__ float s_ker[LMAX], s_reg[LMAX], s_sim[NC][LMAX];
    __shared__ float s_l[NWAVE];
    if (threadIdx.x < LMAX) {
        s_ker[threadIdx.x] = ws->seg_ker[b][threadIdx.x];
        s_reg[threadIdx.x] = ws->seg_reg[b][threadIdx.x];
#pragma unroll
        for (int c = 0; c < NC; ++c) s_sim[c][threadIdx.x] = ws->seg_sim[b][c][threadIdx.x];
    }
    __syncthreads();

    float acc = 0.f;
#pragma unroll
    for (int i = 0; i < IPTV; ++i) {
        const int q = q0 + ((i*TPB + threadIdx.x) << 2);
        const size_t p = pb + q;
        const float4 rg4 = *(const float4*)(regGT + p);
        const float4 s0  = *(const float4*)(sims + ((size_t)(b*NC+0))*HW + q);
        const float4 s1  = *(const float4*)(sims + ((size_t)(b*NC+1))*HW + q);
        const float4 s2  = *(const float4*)(sims + ((size_t)(b*NC+2))*HW + q);
        const float4 s3  = *(const float4*)(sims + ((size_t)(b*NC+3))*HW + q);
        const int4 lk4 = *(const int4*)(labK + p);
        const int4 lr4 = *(const int4*)(labR + p);

        const float rgA[VEC] = {rg4.x, rg4.y, rg4.z, rg4.w};
        const float smA[NC][VEC] = {{s0.x,s0.y,s0.z,s0.w},{s1.x,s1.y,s1.z,s1.w},
                                    {s2.x,s2.y,s2.z,s2.w},{s3.x,s3.y,s3.z,s3.w}};
        const int lkA[VEC] = {lk4.x, lk4.y, lk4.z, lk4.w};
        const int lrA[VEC] = {lr4.x, lr4.y, lr4.z, lr4.w};

#pragma unroll
        for (int j = 0; j < VEC; ++j) {
            const int lk = lkA[j] & (LMAX-1);
            const int lr = lrA[j] & (LMAX-1);
            const float rg = rgA[j];
            const float ck = (lk > 0) ? s_ker[lk] : 0.f;
            const float cr = (lr > 0) ? s_reg[lr] : 0.f;
            const float inv = 1.f / (ck + 1.f);
            float sq = 0.f;
#pragma unroll
            for (int c = 0; c < NC; ++c) {
                const float Fp = smA[c][j] * rg;
                const float G  = (lk > 0) ? s_sim[c][lk] * inv : 0.f;
                const float d  = Fp - G;
                sq += d * d;
            }
            float nr = (sq > 0.f) ? sqrtf(sq) : 0.f;
            nr -= 0.5f;
            nr  = fmaxf(nr, 0.f);
            acc += __logf(nr*nr + 1.f) / (cr + 1.f);
        }
    }
    acc = waveReduceSum(acc);
    const int wid = threadIdx.x >> 6;
    if ((threadIdx.x & 63) == 0) s_l[wid] = acc;
    __syncthreads();
    if (threadIdx.x == 0) {
        float s = 0.f;
#pragma unroll
        for (int w = 0; w < NWAVE; ++w) s += s_l[w];
        unsafeAtomicAdd(&ws->lagg, s);
    }
}

__global__ void pan_finalize(const WS* __restrict__ ws, float* __restrict__ out)
{
    if (threadIdx.x != 0 || blockIdx.x != 0) return;
    const double f0 = log(10.0);
    double Ldis = 0.0;
    for (int b = 0; b < NB; ++b) {
        const int K = ws->kmax[b];
        if (K >= 2) {
            double t1 = 0.0;
            const int lim = (K < LMAX-1) ? K : (LMAX-1);
            for (int l = 1; l <= lim; ++l) {
                float sqS = 0.f;
                for (int c = 0; c < NC; ++c) {
                    const float s = ws->seg_sim[b][c][l];
                    sqS += s * s;
                }
                const float nm  = (sqS > 0.f) ? sqrtf(sqS) : 0.f;
                float gap = 3.0f - nm;
                gap = fmaxf(gap, 0.f);
                const double f = log((double)gap*gap + 1.0);
                t1 += (double)ws->seg_n[b][l] * (f - f0);
            }
            Ldis += (K - 1.0) * t1
                  + (double)K * (K - 1) * 0.5 * (double)NB * (double)HW * f0;
        }
    }
    const double numk = (double)ws->kmax[NB-1];
    const double Lagg = (double)ws->lagg / numk;
    const double lr = 1.0 - (2.0*(double)ws->dice[0] + 1e-6) /
                            ((double)ws->dice[1] + (double)ws->dice[2] + 1e-6);
    const double lk = 1.0 - (2.0*(double)ws->dice[3] + 1e-6) /
                            ((double)ws->dice[4] + (double)ws->dice[5] + 1e-6);
    out[0] = (float)(lr + 0.5*lk + 0.25*(Lagg + Ldis));
}

extern "C" void kernel_launch(void* const* d_in, const int* in_sizes, int n_in,
                              void* d_out, int out_size, void* d_ws, size_t ws_size,
                              hipStream_t stream)
{
    const float* predR = (const float*)d_in[0];
    const float* regGT = (const float*)d_in[1];
    const float* predK = (const float*)d_in[2];
    const float* kerGT = (const float*)d_in[3];
    const float* sims  = (const float*)d_in[4];
    const int*   labR  = (const int*)d_in[5];
    const int*   labK  = (const int*)d_in[6];
    WS* ws = (WS*)d_ws;

    hipMemsetAsync(d_ws, 0, sizeof(WS), stream);

    dim3 grid(NB * BPB), blk(TPB);
    pan_pass1<<<grid, blk, 0, stream>>>(predR, regGT, predK, kerGT, sims, labR, labK, ws);
    pan_pass2<<<grid, blk, 0, stream>>>(regGT, sims, labR, labK, ws);
    pan_finalize<<<1, 64, 0, stream>>>(ws, (float*)d_out);
}